// Round 5
// baseline (681.884 us; speedup 1.0000x reference)
//
#include <hip/hip_runtime.h>
#include <stdint.h>

#define N_NODES 50000
#define N_EDGES 400000
#define MPAD    50048   // 391 * 128
#define SCAN_B  49      // ceil(50000/1024)

typedef __bf16 bf16x8 __attribute__((ext_vector_type(8)));
typedef float  f32x4  __attribute__((ext_vector_type(4)));
typedef unsigned short ushort_t;
typedef unsigned int   uint_t;

// ---------- bf16 helpers (RNE) ----------
__device__ __forceinline__ ushort_t f2b(float f){
    uint_t x = __float_as_uint(f);
    x += 0x7FFFu + ((x >> 16) & 1u);
    return (ushort_t)(x >> 16);
}
__device__ __forceinline__ float b2f(ushort_t h){
    return __uint_as_float(((uint_t)h) << 16);
}

// ---------- CSR build ----------
__global__ void zero_two(int* a, int* b, int n){
    int i = blockIdx.x * blockDim.x + threadIdx.x;
    if (i < n){ a[i] = 0; b[i] = 0; }
}

__global__ void hist_kernel(const int* __restrict__ dst, int* __restrict__ deg, int E){
    int i = blockIdx.x * blockDim.x + threadIdx.x;
    if (i < E) atomicAdd(&deg[dst[i]], 1);
}

// hierarchical scan, stage 1: per-block exclusive scan + block totals
__global__ __launch_bounds__(1024) void blk_scan_kernel(
        const int* __restrict__ deg, int* __restrict__ offs,
        int* __restrict__ bsum, int n){
    __shared__ int buf[1024];
    const int t = threadIdx.x, b = blockIdx.x;
    const int i = b * 1024 + t;
    int v = (i < n) ? deg[i] : 0;
    buf[t] = v; __syncthreads();
    for (int off = 1; off < 1024; off <<= 1){
        int x = (t >= off) ? buf[t - off] : 0;
        __syncthreads();
        buf[t] += x;
        __syncthreads();
    }
    if (i < n) offs[i] = buf[t] - v;         // local exclusive prefix
    if (t == 1023) bsum[b] = buf[1023];      // block total
}

// stage 2: one wave scans the 49 block totals (exclusive)
__global__ void bsum_scan_kernel(int* __restrict__ bsum, int nb){
    int t = threadIdx.x;                      // 64 threads
    int orig = (t < nb) ? bsum[t] : 0;
    int v = orig;
    #pragma unroll
    for (int off = 1; off < 64; off <<= 1){
        int x = __shfl_up(v, off, 64);
        if (t >= off) v += x;
    }
    if (t < nb) bsum[t] = v - orig;           // exclusive
}

// stage 3: add block offsets; set offs[n] = E (constant: every edge lands in [0,n))
__global__ __launch_bounds__(1024) void add_off_kernel(
        int* __restrict__ offs, const int* __restrict__ bsum, int n){
    int i = blockIdx.x * 1024 + threadIdx.x;
    if (i < n) offs[i] += bsum[blockIdx.x];
    if (i == 0) offs[n] = N_EDGES;
}

__global__ void fill_kernel(const int* __restrict__ src, const int* __restrict__ dst,
                            const int* __restrict__ offs, int* __restrict__ cursor,
                            int* __restrict__ nbr, int E){
    int i = blockIdx.x * blockDim.x + threadIdx.x;
    if (i < E){
        int d = dst[i];
        int p = atomicAdd(&cursor[d], 1);
        nbr[offs[d] + p] = src[i];
    }
}

// ---------- dtype conversion ----------
__global__ void f2b_kernel(const float4* __restrict__ in, ushort4* __restrict__ out, int n4){
    int i = blockIdx.x * blockDim.x + threadIdx.x;
    if (i < n4){
        float4 v = in[i];
        ushort4 o; o.x = f2b(v.x); o.y = f2b(v.y); o.z = f2b(v.z); o.w = f2b(v.w);
        out[i] = o;
    }
}

// W [K,N] fp32 -> Wt [N,K] bf16 (coalesced writes)
__global__ void wtrans_kernel(const float* __restrict__ W, ushort_t* __restrict__ Wt,
                              int K, int N){
    int i = blockIdx.x * blockDim.x + threadIdx.x;   // i = n*K + k
    if (i < K * N){
        int n = i / K, k = i - n * K;
        Wt[i] = f2b(W[k * N + n]);
    }
}

// ---------- GEMM: C[M,N] = A[M,K] @ Bt[N,K]^T, bf16, 128x256 block tile ----------
__device__ __forceinline__ void load16(const void* g, void* l){
    __builtin_amdgcn_global_load_lds((const __attribute__((address_space(1))) void*)g,
                                     (__attribute__((address_space(3))) void*)l, 16, 0, 0);
}

// block tile 128(M) x 256(N), BK=32. 4 waves in 2x2: wave tile 64x128.
// grid: (MPAD/128, N/256). Requires N % 256 == 0.
__device__ __forceinline__ void gemm_body(const ushort_t* __restrict__ A,
                                          const ushort_t* __restrict__ Bt,
                                          ushort_t* __restrict__ C,
                                          int N, int K){
    __shared__ ushort_t As[128 * 32];   // 8 KB
    __shared__ ushort_t Bs[256 * 32];   // 16 KB
    const int tid  = threadIdx.x, lane = tid & 63, wave = tid >> 6;
    const int bm = blockIdx.x, bn = blockIdx.y;
    const int fr = lane & 15;           // fragment row within 16
    const int fk = (lane >> 4) * 8;     // fragment k-offset within 32
    const int wm = (wave >> 1) * 64, wn = (wave & 1) * 128;
    f32x4 acc[4][8] = {};

    for (int kt = 0; kt < K; kt += 32){
        __syncthreads();
        // A: 512 slots of 16B; B: 1024 slots. slot s -> row s>>2, col (s&3)*8
        #pragma unroll
        for (int i = 0; i < 2; i++){
            int s = tid + i * 256;
            load16(A + (size_t)(bm * 128 + (s >> 2)) * K + kt + (s & 3) * 8,
                   (char*)As + s * 16);
        }
        #pragma unroll
        for (int i = 0; i < 4; i++){
            int s = tid + i * 256;
            load16(Bt + (size_t)(bn * 256 + (s >> 2)) * K + kt + (s & 3) * 8,
                   (char*)Bs + s * 16);
        }
        __syncthreads();   // drains vmcnt(0): global_load_lds complete
        bf16x8 af[4], bf[8];
        #pragma unroll
        for (int t = 0; t < 4; t++)
            af[t] = *(const bf16x8*)(const void*)(As + (wm + t * 16 + fr) * 32 + fk);
        #pragma unroll
        for (int t = 0; t < 8; t++)
            bf[t] = *(const bf16x8*)(const void*)(Bs + (wn + t * 16 + fr) * 32 + fk);
        #pragma unroll
        for (int tm = 0; tm < 4; tm++)
            #pragma unroll
            for (int tn = 0; tn < 8; tn++)
                acc[tm][tn] = __builtin_amdgcn_mfma_f32_16x16x32_bf16(
                                  af[tm], bf[tn], acc[tm][tn], 0, 0, 0);
    }
    // epilogue: C/D layout col=lane&15, row=(lane>>4)*4+reg  [m89-verified]
    const int r0 = (lane >> 4) * 4, c0 = lane & 15;
    #pragma unroll
    for (int tm = 0; tm < 4; tm++){
        #pragma unroll
        for (int tn = 0; tn < 8; tn++){
            int rbase = bm * 128 + wm + tm * 16 + r0;
            int cidx  = bn * 256 + wn + tn * 16 + c0;
            #pragma unroll
            for (int reg = 0; reg < 4; reg++)
                C[(size_t)(rbase + reg) * N + cidx] = f2b(acc[tm][tn][reg]);
        }
    }
}

// per-layer wrappers (profiler attribution)
__global__ __launch_bounds__(256, 2) void gemm_l0(const ushort_t* __restrict__ A,
        const ushort_t* __restrict__ Bt, ushort_t* __restrict__ C, int N, int K){
    gemm_body(A, Bt, C, N, K);
}
__global__ __launch_bounds__(256, 2) void gemm_l1(const ushort_t* __restrict__ A,
        const ushort_t* __restrict__ Bt, ushort_t* __restrict__ C, int N, int K){
    gemm_body(A, Bt, C, N, K);
}
__global__ __launch_bounds__(256, 2) void gemm_l2(const ushort_t* __restrict__ A,
        const ushort_t* __restrict__ Bt, ushort_t* __restrict__ C, int N, int K){
    gemm_body(A, Bt, C, N, K);
}

// ---------- aggregation: column-sliced (XCD-affine), 8 edge-groups per wave ----------
__device__ __forceinline__ void acc8(float* a, uint4 y){
    a[0] += b2f((ushort_t)(y.x & 0xffff)); a[1] += b2f((ushort_t)(y.x >> 16));
    a[2] += b2f((ushort_t)(y.y & 0xffff)); a[3] += b2f((ushort_t)(y.y >> 16));
    a[4] += b2f((ushort_t)(y.z & 0xffff)); a[5] += b2f((ushort_t)(y.z >> 16));
    a[6] += b2f((ushort_t)(y.w & 0xffff)); a[7] += b2f((ushort_t)(y.w >> 16));
}

// H[v] = relu((sum Y[nbr] + Y[v]) / (deg+1) + b), d=512, bf16 out.
// Wave per (node, 64-col slice). slice = blockIdx & 7 -> XCD-affine: each XCD
// touches only Y[:, slice] = 6.25 MB (vs 4 MB L2/XCD). 8 lane-groups of 8
// process 8 edges concurrently (one 128B line each) -> MLP not degree-capped.
// Self row enters as pseudo-edge at index beg-1 (group 0 only).
__global__ __launch_bounds__(256) void agg_relu_kernel(
        const ushort_t* __restrict__ Y, const int* __restrict__ offs,
        const int* __restrict__ nbr, const float* __restrict__ bias,
        ushort_t* __restrict__ H){
    const int lane = threadIdx.x & 63, wave = threadIdx.x >> 6;
    const int s = blockIdx.x & 7;              // column slice
    const int v = (blockIdx.x >> 3) * 4 + wave;
    const int grp = lane >> 3, sub = lane & 7;
    const int col = s * 64 + sub * 8;
    float a[8] = {0.f,0.f,0.f,0.f,0.f,0.f,0.f,0.f};
    const int beg = offs[v], end = offs[v + 1];
    for (int i = beg - 1 + grp; i < end; i += 8){
        int u = (i < beg) ? v : nbr[i];
        uint4 y = *(const uint4*)(const void*)(Y + (size_t)u * 512 + col);
        acc8(a, y);
    }
    // merge the 8 group partials (lane bits 3..5)
    #pragma unroll
    for (int m = 8; m < 64; m <<= 1){
        #pragma unroll
        for (int j = 0; j < 8; j++)
            a[j] += __shfl_xor(a[j], m, 64);
    }
    if (grp == 0){
        const float inv = 1.0f / (float)(end - beg + 1);
        float4 b0 = *(const float4*)(bias + col);
        float4 b1 = *(const float4*)(bias + col + 4);
        float r[8];
        r[0]=a[0]*inv+b0.x; r[1]=a[1]*inv+b0.y; r[2]=a[2]*inv+b0.z; r[3]=a[3]*inv+b0.w;
        r[4]=a[4]*inv+b1.x; r[5]=a[5]*inv+b1.y; r[6]=a[6]*inv+b1.z; r[7]=a[7]*inv+b1.w;
        #pragma unroll
        for (int j = 0; j < 8; j++) r[j] = r[j] > 0.f ? r[j] : 0.f;
        uint4 o;
        o.x = (uint_t)f2b(r[0]) | ((uint_t)f2b(r[1]) << 16);
        o.y = (uint_t)f2b(r[2]) | ((uint_t)f2b(r[3]) << 16);
        o.z = (uint_t)f2b(r[4]) | ((uint_t)f2b(r[5]) << 16);
        o.w = (uint_t)f2b(r[6]) | ((uint_t)f2b(r[7]) << 16);
        *(uint4*)(void*)(H + (size_t)v * 512 + col) = o;
    }
}

// final layer: d=256, fp32 out, no relu. 4 slices of 64 cols.
__global__ __launch_bounds__(256) void agg_out_kernel(
        const ushort_t* __restrict__ Y, const int* __restrict__ offs,
        const int* __restrict__ nbr, const float* __restrict__ bias,
        float* __restrict__ out){
    const int lane = threadIdx.x & 63, wave = threadIdx.x >> 6;
    const int s = blockIdx.x & 3;              // column slice
    const int v = (blockIdx.x >> 2) * 4 + wave;
    const int grp = lane >> 3, sub = lane & 7;
    const int col = s * 64 + sub * 8;
    float a[8] = {0.f,0.f,0.f,0.f,0.f,0.f,0.f,0.f};
    const int beg = offs[v], end = offs[v + 1];
    for (int i = beg - 1 + grp; i < end; i += 8){
        int u = (i < beg) ? v : nbr[i];
        uint4 y = *(const uint4*)(const void*)(Y + (size_t)u * 256 + col);
        acc8(a, y);
    }
    #pragma unroll
    for (int m = 8; m < 64; m <<= 1){
        #pragma unroll
        for (int j = 0; j < 8; j++)
            a[j] += __shfl_xor(a[j], m, 64);
    }
    if (grp == 0){
        const float inv = 1.0f / (float)(end - beg + 1);
        float4 b0 = *(const float4*)(bias + col);
        float4 b1 = *(const float4*)(bias + col + 4);
        float4 r0, r1;
        r0.x=a[0]*inv+b0.x; r0.y=a[1]*inv+b0.y; r0.z=a[2]*inv+b0.z; r0.w=a[3]*inv+b0.w;
        r1.x=a[4]*inv+b1.x; r1.y=a[5]*inv+b1.y; r1.z=a[6]*inv+b1.z; r1.w=a[7]*inv+b1.w;
        *(float4*)(out + (size_t)v * 256 + col)     = r0;
        *(float4*)(out + (size_t)v * 256 + col + 4) = r1;
    }
}

extern "C" void kernel_launch(void* const* d_in, const int* in_sizes, int n_in,
                              void* d_out, int out_size, void* d_ws, size_t ws_size,
                              hipStream_t stream) {
    const float* feats = (const float*)d_in[0];
    const int*   src   = (const int*)  d_in[1];
    const int*   dst   = (const int*)  d_in[2];
    const float* W0    = (const float*)d_in[3];
    const float* b0    = (const float*)d_in[4];
    const float* W1    = (const float*)d_in[5];
    const float* b1    = (const float*)d_in[6];
    const float* W2    = (const float*)d_in[7];
    const float* b2    = (const float*)d_in[8];
    float* out = (float*)d_out;

    char* w = (char*)d_ws;
    ushort_t* Abuf = (ushort_t*)w;  w += (size_t)MPAD * 512 * 2;   // 51.25 MB
    ushort_t* Ybuf = (ushort_t*)w;  w += (size_t)MPAD * 512 * 2;   // 51.25 MB
    ushort_t* W0t  = (ushort_t*)w;  w += 512 * 512 * 2;
    ushort_t* W1t  = (ushort_t*)w;  w += 512 * 512 * 2;
    ushort_t* W2t  = (ushort_t*)w;  w += 256 * 512 * 2;
    int* deg    = (int*)w;          w += 50048 * 4;
    int* offs   = (int*)w;          w += 50056 * 4;
    int* cursor = (int*)w;          w += 50048 * 4;
    int* nbr    = (int*)w;          w += (size_t)N_EDGES * 4;
    int* bsum   = (int*)w;          w += 64 * 4;
    // total ~106 MB

    // CSR build (re-done every launch; ws is poisoned)
    zero_two<<<(N_NODES + 255) / 256, 256, 0, stream>>>(deg, cursor, N_NODES);
    hist_kernel<<<(N_EDGES + 255) / 256, 256, 0, stream>>>(dst, deg, N_EDGES);
    blk_scan_kernel<<<SCAN_B, 1024, 0, stream>>>(deg, offs, bsum, N_NODES);
    bsum_scan_kernel<<<1, 64, 0, stream>>>(bsum, SCAN_B);
    add_off_kernel<<<SCAN_B, 1024, 0, stream>>>(offs, bsum, N_NODES);
    fill_kernel<<<(N_EDGES + 255) / 256, 256, 0, stream>>>(src, dst, offs, cursor, nbr, N_EDGES);

    // conversions
    int n4 = N_NODES * 512 / 4;
    f2b_kernel<<<(n4 + 255) / 256, 256, 0, stream>>>((const float4*)feats, (ushort4*)Abuf, n4);
    wtrans_kernel<<<(512 * 512 + 255) / 256, 256, 0, stream>>>(W0, W0t, 512, 512);
    wtrans_kernel<<<(512 * 512 + 255) / 256, 256, 0, stream>>>(W1, W1t, 512, 512);
    wtrans_kernel<<<(512 * 256 + 255) / 256, 256, 0, stream>>>(W2, W2t, 512, 256);

    dim3 g01(MPAD / 128, 512 / 256);   // 128x256 tiles
    dim3 g2 (MPAD / 128, 256 / 256);

    // layer 0: Y = A @ W0t^T ; A' = relu((agg Y + Y)/(deg+1) + b0)
    gemm_l0<<<g01, 256, 0, stream>>>(Abuf, W0t, Ybuf, 512, 512);
    agg_relu_kernel<<<(N_NODES / 4) * 8, 256, 0, stream>>>(Ybuf, offs, nbr, b0, Abuf);
    // layer 1
    gemm_l1<<<g01, 256, 0, stream>>>(Abuf, W1t, Ybuf, 512, 512);
    agg_relu_kernel<<<(N_NODES / 4) * 8, 256, 0, stream>>>(Ybuf, offs, nbr, b1, Abuf);
    // layer 2 (no relu, fp32 out)
    gemm_l2<<<g2, 256, 0, stream>>>(Abuf, W2t, Ybuf, 256, 512);
    agg_out_kernel<<<(N_NODES / 4) * 4, 256, 0, stream>>>(Ybuf, offs, nbr, b2, out);
}